// Round 1
// baseline (1361.262 us; speedup 1.0000x reference)
//
#include <hip/hip_runtime.h>

// CapsuleLayer — B=32, I=2048, N=32, D=32, ROUTINGS=3.
// v2: W-stationary restructure. One block per input capsule i (grid 2048,
// 512 threads). Each thread holds TWO W rows (c=2t, 2t+1) in registers,
// loaded from global exactly once (prev version re-read W[i] 32x through
// L2/L3 -> 8.6 GB of cache traffic, the measured bottleneck). x[b,k] is
// wave-uniform -> scalar loads, FMA with SGPR operand. u_hat staged in LDS
// in two 16-batch halves (67.6 KB, stride 33 -> conflict-free), so 2 blocks
// co-reside per CU. Routing phase math identical to the verified version.

#define IC 2048
#define NS 33                 // floats per n-row in LDS (pad +1)
#define UHW (32 * NS)         // 1056 floats per batch row

__device__ __forceinline__ float f_lo(unsigned u) { return __uint_as_float(u << 16); }
__device__ __forceinline__ float f_hi(unsigned u) { return __uint_as_float(u & 0xFFFF0000u); }
__device__ __forceinline__ unsigned short f_to_bfbits(float f) {  // RNE
    unsigned u = __float_as_uint(f);
    u += 0x7FFFu + ((u >> 16) & 1u);
    return (unsigned short)(u >> 16);
}

template<bool FP32>
__device__ __forceinline__ void caps_body(
    const void* __restrict__ xp, const void* __restrict__ Wp,
    void* __restrict__ outp, float (*uh)[UHW],
    unsigned i, unsigned tid)
{
    // ---- W rows c0=2*tid, c1=2*tid+1 -> registers. W[i] read ONCE per block.
    float w0[32], w1[32];
    if (FP32) {
        const float4* wr = (const float4*)(
            (const float*)Wp + (size_t)i * 32768 + (size_t)tid * 64);
        #pragma unroll
        for (int j = 0; j < 8; ++j) {
            const float4 a = wr[j];
            w0[4*j+0] = a.x; w0[4*j+1] = a.y; w0[4*j+2] = a.z; w0[4*j+3] = a.w;
        }
        #pragma unroll
        for (int j = 0; j < 8; ++j) {
            const float4 a = wr[8 + j];
            w1[4*j+0] = a.x; w1[4*j+1] = a.y; w1[4*j+2] = a.z; w1[4*j+3] = a.w;
        }
    } else {
        const uint4* wr = (const uint4*)(
            (const unsigned short*)Wp + (size_t)i * 32768 + (size_t)tid * 64);
        #pragma unroll
        for (int j = 0; j < 4; ++j) {
            const uint4 a = wr[j];
            w0[8*j+0] = f_lo(a.x); w0[8*j+1] = f_hi(a.x);
            w0[8*j+2] = f_lo(a.y); w0[8*j+3] = f_hi(a.y);
            w0[8*j+4] = f_lo(a.z); w0[8*j+5] = f_hi(a.z);
            w0[8*j+6] = f_lo(a.w); w0[8*j+7] = f_hi(a.w);
        }
        #pragma unroll
        for (int j = 0; j < 4; ++j) {
            const uint4 a = wr[4 + j];
            w1[8*j+0] = f_lo(a.x); w1[8*j+1] = f_hi(a.x);
            w1[8*j+2] = f_lo(a.y); w1[8*j+3] = f_hi(a.y);
            w1[8*j+4] = f_lo(a.z); w1[8*j+5] = f_hi(a.z);
            w1[8*j+6] = f_lo(a.w); w1[8*j+7] = f_hi(a.w);
        }
    }

    const unsigned n    = tid >> 4;             // c0>>5
    const unsigned d0   = (tid & 15) * 2;       // c0&31 (even)
    const unsigned wrow = n * NS + d0;

    #pragma unroll 1
    for (unsigned h = 0; h < 2; ++h) {
        // ---- phase 1: u_hat[b, c] for b in this 16-batch half ----
        #pragma unroll 2
        for (unsigned bh = 0; bh < 16; ++bh) {
            const unsigned b = h * 16 + bh;
            float acc0 = 0.f, acc1 = 0.f;
            if (FP32) {
                // x row is wave-uniform -> expect s_load + v_fmac(sgpr) codegen
                const float4* xf = (const float4*)(
                    (const float*)xp + ((size_t)b * IC + i) * 32);
                #pragma unroll
                for (int j = 0; j < 8; ++j) {
                    const float4 v = xf[j];
                    acc0 += v.x*w0[4*j+0] + v.y*w0[4*j+1]
                          + v.z*w0[4*j+2] + v.w*w0[4*j+3];
                    acc1 += v.x*w1[4*j+0] + v.y*w1[4*j+1]
                          + v.z*w1[4*j+2] + v.w*w1[4*j+3];
                }
            } else {
                const uint4* xu = (const uint4*)(
                    (const unsigned short*)xp + ((size_t)b * IC + i) * 32);
                #pragma unroll
                for (int j = 0; j < 4; ++j) {
                    const uint4 v = xu[j];
                    const float x0 = f_lo(v.x), x1 = f_hi(v.x);
                    const float x2 = f_lo(v.y), x3 = f_hi(v.y);
                    const float x4 = f_lo(v.z), x5 = f_hi(v.z);
                    const float x6 = f_lo(v.w), x7 = f_hi(v.w);
                    acc0 += x0*w0[8*j+0] + x1*w0[8*j+1] + x2*w0[8*j+2] + x3*w0[8*j+3]
                          + x4*w0[8*j+4] + x5*w0[8*j+5] + x6*w0[8*j+6] + x7*w0[8*j+7];
                    acc1 += x0*w1[8*j+0] + x1*w1[8*j+1] + x2*w1[8*j+2] + x3*w1[8*j+3]
                          + x4*w1[8*j+4] + x5*w1[8*j+5] + x6*w1[8*j+6] + x7*w1[8*j+7];
                }
            }
            uh[bh][wrow]     = acc0;
            uh[bh][wrow + 1] = acc1;
        }
        __syncthreads();

        // ---- phase 2: routing for 512 (bh, s) pairs == 512 threads ----
        {
            const unsigned bh = tid >> 5, s = tid & 31;
            const float* ub = uh[bh];

            float col[32];   // U[b, n, d=s] — used 3x, keep in regs
            #pragma unroll
            for (int nn = 0; nn < 32; ++nn) col[nn] = ub[nn * NS + s];
            // row U[b, n=s, d] streamed from LDS (used 2x) to cap VGPRs

            float o, r;
            // r=0: softmax(0) = uniform 1/32
            {
                float acc = 0.f;
                #pragma unroll
                for (int nn = 0; nn < 32; ++nn) acc += col[nn];
                o = fmaxf(acc * (1.0f / 32.0f), 0.f);
                float rr = 0.f;
                #pragma unroll
                for (int d = 0; d < 32; ++d) rr += __shfl(o, d, 32) * ub[s * NS + d];
                r = rr;
            }

            #pragma unroll 1
            for (int iter = 1; iter < 3; ++iter) {
                float mx = r;
                #pragma unroll
                for (int off = 16; off >= 1; off >>= 1)
                    mx = fmaxf(mx, __shfl_xor(mx, off, 32));
                const float e = __expf(r - mx);
                float sm = e;
                #pragma unroll
                for (int off = 16; off >= 1; off >>= 1)
                    sm += __shfl_xor(sm, off, 32);
                const float c = e / sm;

                float acc = 0.f;
                #pragma unroll
                for (int nn = 0; nn < 32; ++nn) acc += __shfl(c, nn, 32) * col[nn];
                o = fmaxf(acc, 0.f);

                if (iter < 2) {
                    float rr = 0.f;
                    #pragma unroll
                    for (int d = 0; d < 32; ++d) rr += __shfl(o, d, 32) * ub[s * NS + d];
                    r += rr;
                }
            }

            const size_t oidx = ((size_t)(h * 16 + bh) * IC + i) * 32 + s;
            if (FP32) ((float*)outp)[oidx] = o;
            else      ((unsigned short*)outp)[oidx] = f_to_bfbits(o);
        }
        __syncthreads();   // before next half overwrites uh
    }
}

__global__ __launch_bounds__(512, 4)
void CapsuleLayer_72224170049868_kernel(
    const void* __restrict__ x, const void* __restrict__ W,
    void* __restrict__ out)
{
    __shared__ float uh[16][UHW];   // 67.6 KB -> 2 blocks/CU
    __shared__ int   flagS;

    const unsigned i   = blockIdx.x;    // 0..2047
    const unsigned tid = threadIdx.x;   // 0..511

    // dtype sniff: bf16 even-halfword exponents are <=125 for |W|<0.5;
    // fp32 buffers put random mantissa bits there -> >=126 appears fast.
    if (tid == 0) {
        int f = 0;
        const unsigned* Wu = (const unsigned*)W;
        for (int j = 0; j < 32; ++j)
            if (((Wu[j] >> 7) & 0xFFu) >= 126u) f = 1;
        flagS = f;
    }
    __syncthreads();
    const bool is_fp32 = (flagS != 0);

    if (is_fp32) caps_body<true >(x, W, out, uh, i, tid);
    else         caps_body<false>(x, W, out, uh, i, tid);
}

extern "C" void kernel_launch(void* const* d_in, const int* in_sizes, int n_in,
                              void* d_out, int out_size, void* d_ws, size_t ws_size,
                              hipStream_t stream) {
    (void)d_ws; (void)ws_size; (void)out_size;
    // defensive input-order detection: x = 2,097,152 elems, W = 67,108,864
    const int swap = (n_in >= 2 && in_sizes[0] > in_sizes[1]) ? 1 : 0;
    const void* x = d_in[swap ? 1 : 0];
    const void* W = d_in[swap ? 0 : 1];

    CapsuleLayer_72224170049868_kernel<<<dim3(2048), dim3(512), 0, stream>>>(x, W, d_out);
}

// Round 2
// 528.453 us; speedup vs baseline: 2.5759x; 2.5759x over previous
//
#include <hip/hip_runtime.h>

// CapsuleLayer — B=32, I=2048, N=32, D=32, ROUTINGS=3.
// v3: same W-stationary structure as v2 (one block per capsule i, 512
// threads, each thread holds W rows c=2t,2t+1 in registers across the
// batch loop; u_hat staged in LDS in two 16-batch halves, stride 33).
// v2's failure: __launch_bounds__(512,4) imposed a 64-VGPR cap -> the
// 64-float W live set spilled to scratch -> 4 GB of HBM spill traffic
// (WRITE_SIZE 888 MB vs 8.4 MB output) at 45% of peak BW. Fix: declare
// (512,2) -> 256-VGPR cap. Occupancy is LDS-limited to 2 blocks/CU
// (66.5 KB each) regardless, so the tighter register cap bought nothing.

#define IC 2048
#define NS 33                 // floats per n-row in LDS (pad +1)
#define UHW (32 * NS)         // 1056 floats per batch row

__device__ __forceinline__ float f_lo(unsigned u) { return __uint_as_float(u << 16); }
__device__ __forceinline__ float f_hi(unsigned u) { return __uint_as_float(u & 0xFFFF0000u); }
__device__ __forceinline__ unsigned short f_to_bfbits(float f) {  // RNE
    unsigned u = __float_as_uint(f);
    u += 0x7FFFu + ((u >> 16) & 1u);
    return (unsigned short)(u >> 16);
}

template<bool FP32>
__device__ __forceinline__ void caps_body(
    const void* __restrict__ xp, const void* __restrict__ Wp,
    void* __restrict__ outp, float (*uh)[UHW],
    unsigned i, unsigned tid)
{
    // ---- W rows c0=2*tid, c1=2*tid+1 -> registers. W[i] read ONCE per block.
    float w0[32], w1[32];
    if (FP32) {
        const float4* wr = (const float4*)(
            (const float*)Wp + (size_t)i * 32768 + (size_t)tid * 64);
        #pragma unroll
        for (int j = 0; j < 8; ++j) {
            const float4 a = wr[j];
            w0[4*j+0] = a.x; w0[4*j+1] = a.y; w0[4*j+2] = a.z; w0[4*j+3] = a.w;
        }
        #pragma unroll
        for (int j = 0; j < 8; ++j) {
            const float4 a = wr[8 + j];
            w1[4*j+0] = a.x; w1[4*j+1] = a.y; w1[4*j+2] = a.z; w1[4*j+3] = a.w;
        }
    } else {
        const uint4* wr = (const uint4*)(
            (const unsigned short*)Wp + (size_t)i * 32768 + (size_t)tid * 64);
        #pragma unroll
        for (int j = 0; j < 4; ++j) {
            const uint4 a = wr[j];
            w0[8*j+0] = f_lo(a.x); w0[8*j+1] = f_hi(a.x);
            w0[8*j+2] = f_lo(a.y); w0[8*j+3] = f_hi(a.y);
            w0[8*j+4] = f_lo(a.z); w0[8*j+5] = f_hi(a.z);
            w0[8*j+6] = f_lo(a.w); w0[8*j+7] = f_hi(a.w);
        }
        #pragma unroll
        for (int j = 0; j < 4; ++j) {
            const uint4 a = wr[4 + j];
            w1[8*j+0] = f_lo(a.x); w1[8*j+1] = f_hi(a.x);
            w1[8*j+2] = f_lo(a.y); w1[8*j+3] = f_hi(a.y);
            w1[8*j+4] = f_lo(a.z); w1[8*j+5] = f_hi(a.z);
            w1[8*j+6] = f_lo(a.w); w1[8*j+7] = f_hi(a.w);
        }
    }

    const unsigned n    = tid >> 4;             // c0>>5
    const unsigned d0   = (tid & 15) * 2;       // c0&31 (even)
    const unsigned wrow = n * NS + d0;

    #pragma unroll 1
    for (unsigned h = 0; h < 2; ++h) {
        // ---- phase 1: u_hat[b, c] for b in this 16-batch half ----
        #pragma unroll 2
        for (unsigned bh = 0; bh < 16; ++bh) {
            const unsigned b = h * 16 + bh;
            float acc0 = 0.f, acc1 = 0.f;
            if (FP32) {
                // x row is wave-uniform -> s_load + v_fmac(sgpr) codegen
                const float4* xf = (const float4*)(
                    (const float*)xp + ((size_t)b * IC + i) * 32);
                #pragma unroll
                for (int j = 0; j < 8; ++j) {
                    const float4 v = xf[j];
                    acc0 += v.x*w0[4*j+0] + v.y*w0[4*j+1]
                          + v.z*w0[4*j+2] + v.w*w0[4*j+3];
                    acc1 += v.x*w1[4*j+0] + v.y*w1[4*j+1]
                          + v.z*w1[4*j+2] + v.w*w1[4*j+3];
                }
            } else {
                const uint4* xu = (const uint4*)(
                    (const unsigned short*)xp + ((size_t)b * IC + i) * 32);
                #pragma unroll
                for (int j = 0; j < 4; ++j) {
                    const uint4 v = xu[j];
                    const float x0 = f_lo(v.x), x1 = f_hi(v.x);
                    const float x2 = f_lo(v.y), x3 = f_hi(v.y);
                    const float x4 = f_lo(v.z), x5 = f_hi(v.z);
                    const float x6 = f_lo(v.w), x7 = f_hi(v.w);
                    acc0 += x0*w0[8*j+0] + x1*w0[8*j+1] + x2*w0[8*j+2] + x3*w0[8*j+3]
                          + x4*w0[8*j+4] + x5*w0[8*j+5] + x6*w0[8*j+6] + x7*w0[8*j+7];
                    acc1 += x0*w1[8*j+0] + x1*w1[8*j+1] + x2*w1[8*j+2] + x3*w1[8*j+3]
                          + x4*w1[8*j+4] + x5*w1[8*j+5] + x6*w1[8*j+6] + x7*w1[8*j+7];
                }
            }
            uh[bh][wrow]     = acc0;
            uh[bh][wrow + 1] = acc1;
        }
        __syncthreads();

        // ---- phase 2: routing for 512 (bh, s) pairs == 512 threads ----
        {
            const unsigned bh = tid >> 5, s = tid & 31;
            const float* ub = uh[bh];

            float col[32];   // U[b, n, d=s] — used 3x, keep in regs
            #pragma unroll
            for (int nn = 0; nn < 32; ++nn) col[nn] = ub[nn * NS + s];
            // row U[b, n=s, d] streamed from LDS (used 2x) to cap VGPRs

            float o, r;
            // r=0: softmax(0) = uniform 1/32
            {
                float acc = 0.f;
                #pragma unroll
                for (int nn = 0; nn < 32; ++nn) acc += col[nn];
                o = fmaxf(acc * (1.0f / 32.0f), 0.f);
                float rr = 0.f;
                #pragma unroll
                for (int d = 0; d < 32; ++d) rr += __shfl(o, d, 32) * ub[s * NS + d];
                r = rr;
            }

            #pragma unroll 1
            for (int iter = 1; iter < 3; ++iter) {
                float mx = r;
                #pragma unroll
                for (int off = 16; off >= 1; off >>= 1)
                    mx = fmaxf(mx, __shfl_xor(mx, off, 32));
                const float e = __expf(r - mx);
                float sm = e;
                #pragma unroll
                for (int off = 16; off >= 1; off >>= 1)
                    sm += __shfl_xor(sm, off, 32);
                const float c = e / sm;

                float acc = 0.f;
                #pragma unroll
                for (int nn = 0; nn < 32; ++nn) acc += __shfl(c, nn, 32) * col[nn];
                o = fmaxf(acc, 0.f);

                if (iter < 2) {
                    float rr = 0.f;
                    #pragma unroll
                    for (int d = 0; d < 32; ++d) rr += __shfl(o, d, 32) * ub[s * NS + d];
                    r += rr;
                }
            }

            const size_t oidx = ((size_t)(h * 16 + bh) * IC + i) * 32 + s;
            if (FP32) ((float*)outp)[oidx] = o;
            else      ((unsigned short*)outp)[oidx] = f_to_bfbits(o);
        }
        __syncthreads();   // before next half overwrites uh
    }
}

__global__ __launch_bounds__(512, 2)
void CapsuleLayer_72224170049868_kernel(
    const void* __restrict__ x, const void* __restrict__ W,
    void* __restrict__ out)
{
    __shared__ float uh[16][UHW];   // 67.6 KB -> 2 blocks/CU (LDS-limited)
    __shared__ int   flagS;

    const unsigned i   = blockIdx.x;    // 0..2047
    const unsigned tid = threadIdx.x;   // 0..511

    // dtype sniff: bf16 even-halfword exponents are <=125 for |W|<0.5;
    // fp32 buffers put random mantissa bits there -> >=126 appears fast.
    if (tid == 0) {
        int f = 0;
        const unsigned* Wu = (const unsigned*)W;
        for (int j = 0; j < 32; ++j)
            if (((Wu[j] >> 7) & 0xFFu) >= 126u) f = 1;
        flagS = f;
    }
    __syncthreads();
    const bool is_fp32 = (flagS != 0);

    if (is_fp32) caps_body<true >(x, W, out, uh, i, tid);
    else         caps_body<false>(x, W, out, uh, i, tid);
}

extern "C" void kernel_launch(void* const* d_in, const int* in_sizes, int n_in,
                              void* d_out, int out_size, void* d_ws, size_t ws_size,
                              hipStream_t stream) {
    (void)d_ws; (void)ws_size; (void)out_size;
    // defensive input-order detection: x = 2,097,152 elems, W = 67,108,864
    const int swap = (n_in >= 2 && in_sizes[0] > in_sizes[1]) ? 1 : 0;
    const void* x = d_in[swap ? 1 : 0];
    const void* W = d_in[swap ? 0 : 1];

    CapsuleLayer_72224170049868_kernel<<<dim3(2048), dim3(512), 0, stream>>>(x, W, d_out);
}